// Round 4
// baseline (112.802 us; speedup 1.0000x reference)
//
#include <hip/hip_runtime.h>
#include <hip/hip_bf16.h>

typedef __attribute__((ext_vector_type(8))) short bf16x8;
typedef __attribute__((ext_vector_type(4))) float f32x4;

__device__ __forceinline__ float bf2f(unsigned short u) {
    union { unsigned int i; float f; } c; c.i = ((unsigned int)u) << 16; return c.f;
}
__device__ __forceinline__ unsigned short f2bf(float f) {
    union { float f; unsigned int i; } c; c.f = f;
    unsigned int x = c.i;
    x += 0x7fffu + ((x >> 16) & 1u);   // round-to-nearest-even
    return (unsigned short)(x >> 16);
}
// pack two f32 -> bf16x2 (RNE) via v_cvt_pk_bf16_f32
__device__ __forceinline__ unsigned int pk2(float a, float b) {
    __hip_bfloat162 h = __float22bfloat162_rn(float2{a, b});
    union { __hip_bfloat162 h; unsigned int u; } c; c.h = h; return c.u;
}
__device__ __forceinline__ float tanh_fast(float v) {
    float a = fabsf(v);
    a = fminf(a, 15.0f);
    float e = __expf(2.0f * a);
    float t = 1.0f - 2.0f / (e + 1.0f);
    return copysignf(t, v);
}

// async global->LDS, 16B per lane; lptr must be wave-uniform, gptr per-lane
#define GLOAD_LDS16(gp, lp) \
    __builtin_amdgcn_global_load_lds((const __attribute__((address_space(1))) void*)(gp), \
                                     (__attribute__((address_space(3))) void*)(lp), 16, 0, 0)

#define MFMA(a, b, c) __builtin_amdgcn_mfma_f32_16x16x32_bf16((a), (b), (c), 0, 0, 0)

#define SBAR()  __builtin_amdgcn_s_barrier()
#define SCHED0() __builtin_amdgcn_sched_barrier(0)

// ---------------- small reductions ----------------

// sum over t of x -> sumx[b][d] (atomic partials; sumx pre-zeroed)
__global__ void k_sumx(const float* __restrict__ x, float* __restrict__ sumx) {
    int b = blockIdx.x, tc = blockIdx.y;
    int tid = threadIdx.x;
    const float* xp = x + ((size_t)b * 1024 + tc * 64) * 512;
    float a0 = 0.f, a1 = 0.f;
    for (int t = 0; t < 64; ++t) {
        a0 += xp[(size_t)t * 512 + tid];
        a1 += xp[(size_t)t * 512 + tid + 256];
    }
    atomicAdd(&sumx[b * 512 + tid], a0);
    atomicAdd(&sumx[b * 512 + tid + 256], a1);
}

// Abf[i][k] = bf16(m1w[i][k]) (natural order; K index k = e*8+s), fused with
// bias2[i] = sum_k m1w[i,k] * b_ent[(k&7)*512 + (k>>3)]
__global__ void k_prepA(const float* __restrict__ m1w, const float* __restrict__ bent,
                        unsigned short* __restrict__ Abf, float* __restrict__ bias2) {
    int i = blockIdx.x, tid = threadIdx.x;
    const float* row = m1w + (size_t)i * 4096;
    float acc = 0.f;
    #pragma unroll
    for (int q = 0; q < 4; ++q) {
        int col = q * 1024 + tid * 4;
        float4 v = *(const float4*)(row + col);
        ushort4 o;
        o.x = f2bf(v.x); o.y = f2bf(v.y); o.z = f2bf(v.z); o.w = f2bf(v.w);
        *(ushort4*)(Abf + (size_t)i * 4096 + col) = o;
        int e0 = col >> 3, s0 = col & 7;   // col % 4 == 0, so s0 in {0,4}; no e crossing
        acc += v.x * bent[(s0    ) * 512 + e0];
        acc += v.y * bent[(s0 + 1) * 512 + e0];
        acc += v.z * bent[(s0 + 2) * 512 + e0];
        acc += v.w * bent[(s0 + 3) * 512 + e0];
    }
    #pragma unroll
    for (int off = 32; off; off >>= 1) acc += __shfl_xor(acc, off);
    __shared__ float r4[4];
    if ((tid & 63) == 0) r4[tid >> 6] = acc;
    __syncthreads();
    if (tid == 0) bias2[i] = r4[0] + r4[1] + r4[2] + r4[3];
}

// WT[j][k] = bf16(W_ent[(k&7)*512 + (k>>3)][j]); k = e*8+s
__global__ void k_conv_W(const float* __restrict__ W, unsigned short* __restrict__ WT) {
    __shared__ float tile[128][33];
    int e0 = blockIdx.x * 16;
    int j0 = blockIdx.y * 32;
    int tid = threadIdx.x;
    int tx = tid & 31, ty = tid >> 5;
    #pragma unroll
    for (int q = 0; q < 16; ++q) {
        int lk = q * 8 + ty;              // local k = de*8+s, 0..127
        int de = lk >> 3, s = lk & 7;
        int r = s * 512 + e0 + de;
        tile[lk][tx] = W[(size_t)r * 1024 + j0 + tx];
    }
    __syncthreads();
    int j = tid >> 3, ck = (tid & 7) * 16;
    unsigned short* dst = WT + (size_t)(j0 + j) * 4096 + e0 * 8 + ck;
    #pragma unroll
    for (int g = 0; g < 4; ++g) {
        ushort4 o;
        o.x = f2bf(tile[ck + g * 4 + 0][j]);
        o.y = f2bf(tile[ck + g * 4 + 1][j]);
        o.z = f2bf(tile[ck + g * 4 + 2][j]);
        o.w = f2bf(tile[ck + g * 4 + 3][j]);
        *(ushort4*)(dst + g * 4) = o;
    }
}

// ---------------- GEMM1 (split-K=8, pipelined): C[i,j] = sum_k Abf[i,k] WT[j,k] ----------------
__launch_bounds__(512, 2)
__global__ void k_gemm1(const unsigned short* __restrict__ Abf,
                        const unsigned short* __restrict__ WT,
                        float* __restrict__ CpL, float* __restrict__ CpR) {
    __shared__ __align__(16) unsigned short sA[2][64 * 64];
    __shared__ __align__(16) unsigned short sB[2][256 * 64];
    int i0 = blockIdx.x * 64;
    int j0 = blockIdx.y * 256;
    int kbase = blockIdx.z * 512;
    int tid = threadIdx.x, lane = tid & 63, w = tid >> 6;
    int wm = w >> 2, wn = w & 3;
    int lr = lane >> 3, sl = lane & 7;
    int lo = lane & 15, hi = lane >> 4;
    int arow = w * 8 + lr;  // arow&7 == lr
    const unsigned short* gA = Abf + (size_t)(i0 + arow) * 4096 + kbase + ((sl ^ lr) << 3);
    const unsigned short* gB0 = WT + (size_t)(j0 + w * 32 + 0 * 8 + lr) * 4096 + kbase + ((sl ^ lr) << 3);
    const unsigned short* gB1 = WT + (size_t)(j0 + w * 32 + 1 * 8 + lr) * 4096 + kbase + ((sl ^ lr) << 3);
    const unsigned short* gB2 = WT + (size_t)(j0 + w * 32 + 2 * 8 + lr) * 4096 + kbase + ((sl ^ lr) << 3);
    const unsigned short* gB3 = WT + (size_t)(j0 + w * 32 + 3 * 8 + lr) * 4096 + kbase + ((sl ^ lr) << 3);
    bool left = (blockIdx.y < 2);
    f32x4 acc[2][4] = {};

#define G1_STAGE(tt, bufn)                                                    \
    do {                                                                      \
        int koff = (tt) * 64;                                                 \
        GLOAD_LDS16(gA + koff, &sA[bufn][w * 8 * 64]);                        \
        GLOAD_LDS16(gB0 + koff, &sB[bufn][(w * 32 + 0) * 64]);                \
        GLOAD_LDS16(gB1 + koff, &sB[bufn][(w * 32 + 8) * 64]);                \
        GLOAD_LDS16(gB2 + koff, &sB[bufn][(w * 32 + 16) * 64]);               \
        GLOAD_LDS16(gB3 + koff, &sB[bufn][(w * 32 + 24) * 64]);               \
        SCHED0();                                                             \
    } while (0)

    G1_STAGE(0, 0);
    #pragma unroll
    for (int t = 0; t < 8; ++t) {
        int buf = t & 1;
        if (t < 7) {
            G1_STAGE(t + 1, buf ^ 1);
            asm volatile("s_waitcnt vmcnt(5)" ::: "memory");
        } else {
            asm volatile("s_waitcnt vmcnt(0)" ::: "memory");
        }
        SCHED0(); SBAR(); SCHED0();
        __builtin_amdgcn_s_setprio(1);
        #pragma unroll
        for (int kk = 0; kk < 2; ++kk) {
            int slotX = ((kk * 4 + hi) ^ (lo & 7)) << 3;
            bf16x8 a0 = *(const bf16x8*)(&sA[buf][(wm * 32 +      lo) * 64 + slotX]);
            bf16x8 a1 = *(const bf16x8*)(&sA[buf][(wm * 32 + 16 + lo) * 64 + slotX]);
            #pragma unroll
            for (int n = 0; n < 4; ++n) {
                bf16x8 bb = *(const bf16x8*)(&sB[buf][(wn * 64 + n * 16 + lo) * 64 + slotX]);
                if (left) {
                    acc[0][n] = MFMA(a0, bb, acc[0][n]);
                    acc[1][n] = MFMA(a1, bb, acc[1][n]);
                } else {
                    acc[0][n] = MFMA(bb, a0, acc[0][n]);
                    acc[1][n] = MFMA(bb, a1, acc[1][n]);
                }
            }
        }
        __builtin_amdgcn_s_setprio(0);
        if (t < 7) { SCHED0(); SBAR(); SCHED0(); }
    }
#undef G1_STAGE

    int ksoff = blockIdx.z * 262144;
    if (left) {
        #pragma unroll
        for (int m = 0; m < 2; ++m) {
            int ib = i0 + wm * 32 + m * 16 + hi * 4;
            #pragma unroll
            for (int n = 0; n < 4; ++n) {
                int j = j0 + wn * 64 + n * 16 + lo;
                #pragma unroll
                for (int r = 0; r < 4; ++r)
                    CpL[ksoff + (ib + r) * 512 + j] = acc[m][n][r];
            }
        }
    } else {
        #pragma unroll
        for (int m = 0; m < 2; ++m) {
            int ic = i0 + wm * 32 + m * 16 + lo;
            #pragma unroll
            for (int n = 0; n < 4; ++n) {
                int db = j0 - 512 + wn * 64 + n * 16 + hi * 4;
                #pragma unroll
                for (int r = 0; r < 4; ++r)
                    CpR[ksoff + (db + r) * 512 + ic] = acc[m][n][r];
            }
        }
    }
}

// sum 8 split-K partials -> bf16.
// blocks 0..255: M1, written FRAGMENT-LINEAR: elem (i,k) at
//   ((i>>4)*16 + (k>>5))*512 + ((k>>3)&3)*128 + (i&15)*8 + (k&7)
// so a 16x32 MFMA A-frag is one contiguous 1KB run (lane*8 within frag).
// blocks 256..511: M2t stays row-major [d][i].
__global__ void k_reduce(const float* __restrict__ CpL, const float* __restrict__ CpR,
                         unsigned short* __restrict__ M1f, unsigned short* __restrict__ M2t) {
    int bx = blockIdx.x;
    const float* Cp = (bx < 256) ? CpL : CpR;
    int gid = (bx & 255) * 256 + threadIdx.x;   // x4 floats
    float4 s = ((const float4*)Cp)[gid];
    #pragma unroll
    for (int ks = 1; ks < 8; ++ks) {
        float4 t = ((const float4*)Cp)[ks * 65536 + gid];
        s.x += t.x; s.y += t.y; s.z += t.z; s.w += t.w;
    }
    ushort4 o;
    o.x = f2bf(s.x); o.y = f2bf(s.y); o.z = f2bf(s.z); o.w = f2bf(s.w);
    if (bx < 256) {
        int i = gid >> 7, k = (gid & 127) << 2;
        size_t off = ((size_t)((i >> 4) * 16 + (k >> 5)) << 9)
                   + (((k >> 3) & 3) << 7) + ((i & 15) << 3) + (k & 7);
        *(ushort4*)(M1f + off) = o;
    } else {
        ((ushort4*)M2t)[gid] = o;
    }
}

// cb[b][i] = (1/T) * sum_d sumx[b][d]*M2t[d][i] + bias2[i] + m1b[i]
__global__ void k_cb(const float* __restrict__ sumx, const unsigned short* __restrict__ M2t,
                     const float* __restrict__ bias2, const float* __restrict__ m1b,
                     float* __restrict__ cbo) {
    int b = blockIdx.x, i0 = blockIdx.y * 64;
    int tid = threadIdx.x;
    int il = tid & 63, dq = tid >> 6;
    const float* sx = sumx + b * 512 + dq * 128;
    const unsigned short* mp = M2t + (size_t)dq * 128 * 512 + i0 + il;
    float acc = 0.f;
    #pragma unroll 4
    for (int dd = 0; dd < 128; ++dd)
        acc += sx[dd] * bf2f(mp[(size_t)dd * 512]);
    __shared__ float sPart[4][64];
    sPart[dq][il] = acc;
    __syncthreads();
    if (tid < 64) {
        float v = sPart[0][tid] + sPart[1][tid] + sPart[2][tid] + sPart[3][tid];
        cbo[b * 512 + i0 + tid] = v * (1.0f / 1024.0f) + bias2[i0 + tid] + m1b[i0 + tid];
    }
}

// ---------------- GEMM2 + fused LN/tanh/logit — DIRECT-REG (no LDS operands, no K-loop barriers)
// Computes C^T: C[i][bt] = sum_k M1[i,k] * x[bt,k]  via mfma(A=M1frag, B=xfrag).
// Block: 64 bt-rows, 512 thr = 8 waves; wave w owns i in [w*64, w*64+64), all 64 bt.
// A-frags from fragment-linear M1f (1KB contiguous per frag, L2-resident).
// B-frags from f32 x directly (v_cvt_pk_bf16_f32); all 8 waves share the same
// 8KB x-slice per K-step -> L1 hits. LN is over i = rows of C^T.
__launch_bounds__(512)
__global__ void k_gemm2(const float* __restrict__ x,
                        const unsigned short* __restrict__ M1f,
                        const float* __restrict__ cb,
                        const float* __restrict__ lng, const float* __restrict__ lnb,
                        const float* __restrict__ m2w, const float* __restrict__ m2b,
                        float* __restrict__ logits) {
    __shared__ float sStat[8][2][64];
    __shared__ float sMu[64], sRs[64];
    __shared__ float sLp[8][64];
    int bt0 = blockIdx.x * 64;
    int b = bt0 >> 10;
    int tid = threadIdx.x, lane = tid & 63, w = tid >> 6;
    int lo = lane & 15, hi = lane >> 4;
    // A-frag (m,fk) base: frag id = (w*4+m)*16 + fk, each frag 512 elems, lane gets 8
    const unsigned short* aP = M1f + ((size_t)(w * 4 * 16) << 9) + lane * 8;
    // x row pointers for the 4 bt-frags
    const float* xr0 = x + (size_t)(bt0 +  0 + lo) * 512 + hi * 8;
    const float* xr1 = x + (size_t)(bt0 + 16 + lo) * 512 + hi * 8;
    const float* xr2 = x + (size_t)(bt0 + 32 + lo) * 512 + hi * 8;
    const float* xr3 = x + (size_t)(bt0 + 48 + lo) * 512 + hi * 8;
    f32x4 acc[4][4] = {};
    #pragma unroll 4
    for (int fk = 0; fk < 16; ++fk) {
        bf16x8 av[4], bv[4];
        #pragma unroll
        for (int m = 0; m < 4; ++m)
            av[m] = *(const bf16x8*)(aP + ((m * 16 + fk) << 9));
        {
            float4 f0, f1;
            union { unsigned int u[4]; bf16x8 v; } pk;
            f0 = *(const float4*)(xr0 + fk * 32); f1 = *(const float4*)(xr0 + fk * 32 + 4);
            pk.u[0] = pk2(f0.x, f0.y); pk.u[1] = pk2(f0.z, f0.w);
            pk.u[2] = pk2(f1.x, f1.y); pk.u[3] = pk2(f1.z, f1.w);
            bv[0] = pk.v;
            f0 = *(const float4*)(xr1 + fk * 32); f1 = *(const float4*)(xr1 + fk * 32 + 4);
            pk.u[0] = pk2(f0.x, f0.y); pk.u[1] = pk2(f0.z, f0.w);
            pk.u[2] = pk2(f1.x, f1.y); pk.u[3] = pk2(f1.z, f1.w);
            bv[1] = pk.v;
            f0 = *(const float4*)(xr2 + fk * 32); f1 = *(const float4*)(xr2 + fk * 32 + 4);
            pk.u[0] = pk2(f0.x, f0.y); pk.u[1] = pk2(f0.z, f0.w);
            pk.u[2] = pk2(f1.x, f1.y); pk.u[3] = pk2(f1.z, f1.w);
            bv[2] = pk.v;
            f0 = *(const float4*)(xr3 + fk * 32); f1 = *(const float4*)(xr3 + fk * 32 + 4);
            pk.u[0] = pk2(f0.x, f0.y); pk.u[1] = pk2(f0.z, f0.w);
            pk.u[2] = pk2(f1.x, f1.y); pk.u[3] = pk2(f1.z, f1.w);
            bv[3] = pk.v;
        }
        #pragma unroll
        for (int m = 0; m < 4; ++m)
            #pragma unroll
            for (int n = 0; n < 4; ++n)
                acc[m][n] = MFMA(av[m], bv[n], acc[m][n]);
    }
    // add cb (depends on i = row of C^T; broadcast over bt)
    #pragma unroll
    for (int m = 0; m < 4; ++m) {
        float4 c4 = *(const float4*)(cb + b * 512 + w * 64 + m * 16 + hi * 4);
        #pragma unroll
        for (int n = 0; n < 4; ++n) {
            acc[m][n][0] += c4.x; acc[m][n][1] += c4.y;
            acc[m][n][2] += c4.z; acc[m][n][3] += c4.w;
        }
    }
    // LN stats over i (this wave's 64 i's): per-lane sum over (m,r), combine hi-groups
    float s1[4], s2[4];
    #pragma unroll
    for (int n = 0; n < 4; ++n) {
        float a1 = 0.f, a2 = 0.f;
        #pragma unroll
        for (int m = 0; m < 4; ++m)
            #pragma unroll
            for (int r = 0; r < 4; ++r) { float t = acc[m][n][r]; a1 += t; a2 += t * t; }
        a1 += __shfl_xor(a1, 16); a1 += __shfl_xor(a1, 32);
        a2 += __shfl_xor(a2, 16); a2 += __shfl_xor(a2, 32);
        s1[n] = a1; s2[n] = a2;
    }
    if (lane < 16) {
        #pragma unroll
        for (int n = 0; n < 4; ++n) {
            sStat[w][0][n * 16 + lane] = s1[n];
            sStat[w][1][n * 16 + lane] = s2[n];
        }
    }
    __syncthreads();
    if (tid < 64) {
        float a1 = 0.f, a2 = 0.f;
        #pragma unroll
        for (int ww = 0; ww < 8; ++ww) { a1 += sStat[ww][0][tid]; a2 += sStat[ww][1][tid]; }
        float mu = a1 * (1.0f / 512.0f);
        float var = a2 * (1.0f / 512.0f) - mu * mu;
        sMu[tid] = mu;
        sRs[tid] = rsqrtf(var + 1e-5f);
    }
    __syncthreads();
    // per-lane LN params for this wave's i's: i = w*64 + m*16 + hi*4 + r
    float4 g4[4], b4[4], w4[4];
    #pragma unroll
    for (int m = 0; m < 4; ++m) {
        int ib = w * 64 + m * 16 + hi * 4;
        g4[m] = *(const float4*)(lng + ib);
        b4[m] = *(const float4*)(lnb + ib);
        w4[m] = *(const float4*)(m2w + ib);
    }
    float lg[4];
    #pragma unroll
    for (int n = 0; n < 4; ++n) {
        float mu = sMu[n * 16 + lo], rs = sRs[n * 16 + lo];
        float a = 0.f;
        #pragma unroll
        for (int m = 0; m < 4; ++m) {
            a += tanh_fast((acc[m][n][0] - mu) * rs * g4[m].x + b4[m].x) * w4[m].x;
            a += tanh_fast((acc[m][n][1] - mu) * rs * g4[m].y + b4[m].y) * w4[m].y;
            a += tanh_fast((acc[m][n][2] - mu) * rs * g4[m].z + b4[m].z) * w4[m].z;
            a += tanh_fast((acc[m][n][3] - mu) * rs * g4[m].w + b4[m].w) * w4[m].w;
        }
        a += __shfl_xor(a, 16); a += __shfl_xor(a, 32);
        lg[n] = a;
    }
    if (lane < 16) {
        #pragma unroll
        for (int n = 0; n < 4; ++n) sLp[w][n * 16 + lane] = lg[n];
    }
    __syncthreads();
    if (tid < 64) {
        float t = 0.f;
        #pragma unroll
        for (int ww = 0; ww < 8; ++ww) t += sLp[ww][tid];
        logits[bt0 + tid] = t + m2b[0];
    }
}

// ---------------- softmax over T and context ----------------
__global__ void k_softmax(const float* __restrict__ logits, float* __restrict__ wout) {
    int b = blockIdx.x, tid = threadIdx.x;   // 256 threads, 4 t each
    __shared__ float red[4];
    float4 v = ((const float4*)(logits + b * 1024))[tid];
    float mx = fmaxf(fmaxf(v.x, v.y), fmaxf(v.z, v.w));
    for (int off = 32; off; off >>= 1) mx = fmaxf(mx, __shfl_xor(mx, off));
    if ((tid & 63) == 0) red[tid >> 6] = mx;
    __syncthreads();
    mx = fmaxf(fmaxf(red[0], red[1]), fmaxf(red[2], red[3]));
    float e0 = expf(v.x - mx), e1 = expf(v.y - mx), e2 = expf(v.z - mx), e3 = expf(v.w - mx);
    float sm = e0 + e1 + e2 + e3;
    for (int off = 32; off; off >>= 1) sm += __shfl_xor(sm, off);
    __syncthreads();
    if ((tid & 63) == 0) red[tid >> 6] = sm;
    __syncthreads();
    float inv = 1.0f / (red[0] + red[1] + red[2] + red[3]);
    float4 o; o.x = e0 * inv; o.y = e1 * inv; o.z = e2 * inv; o.w = e3 * inv;
    ((float4*)(wout + b * 1024))[tid] = o;
}

// context[b][d] = sum_t w[b][t] * x[b][t][d]  (atomic partials; ctx pre-zeroed)
__global__ void k_context(const float* __restrict__ x, const float* __restrict__ wts,
                          float* __restrict__ ctx) {
    int b = blockIdx.x, tc = blockIdx.y;
    int tid = threadIdx.x;
    const float* xp = x + ((size_t)b * 1024 + tc * 64) * 512;
    const float* wp = wts + b * 1024 + tc * 64;
    float a0 = 0.f, a1 = 0.f;
    for (int t = 0; t < 64; ++t) {
        float wv = wp[t];
        a0 += wv * xp[(size_t)t * 512 + tid];
        a1 += wv * xp[(size_t)t * 512 + tid + 256];
    }
    atomicAdd(&ctx[b * 512 + tid], a0);
    atomicAdd(&ctx[b * 512 + tid + 256], a1);
}

// ---------------- launch ----------------
extern "C" void kernel_launch(void* const* d_in, const int* in_sizes, int n_in,
                              void* d_out, int out_size, void* d_ws, size_t ws_size,
                              hipStream_t stream) {
    (void)in_sizes; (void)n_in; (void)out_size; (void)ws_size;
    const float* x    = (const float*)d_in[0];
    const float* Went = (const float*)d_in[1];
    const float* bent = (const float*)d_in[2];
    const float* m1w  = (const float*)d_in[3];
    const float* m1b  = (const float*)d_in[4];
    const float* lng  = (const float*)d_in[5];
    const float* lnb  = (const float*)d_in[6];
    const float* m2w  = (const float*)d_in[7];
    const float* m2b  = (const float*)d_in[8];
    float* out = (float*)d_out;            // [0,8192): context ; [8192,24576): attn
    char* ws = (char*)d_ws;

    unsigned short* Abf   = (unsigned short*)(ws);                        // 4 MB
    unsigned short* WT    = (unsigned short*)(ws + 4194304);              // 8 MB
    float* CpL            = (float*)(ws + 12582912);                      // 8 MB
    float* CpR            = (float*)(ws + 20971520);                      // 8 MB
    unsigned short* M1f   = (unsigned short*)(ws + 29360128);             // 512 KB (frag-linear)
    unsigned short* M2t   = (unsigned short*)(ws + 29884416);             // 512 KB
    float* sumx   = (float*)(ws + 30408704);                              // 32 KB
    float* bias2  = (float*)(ws + 30441472);                              // 2 KB
    float* cb     = (float*)(ws + 30443520);                              // 32 KB
    float* logits = (float*)(ws + 30476288);                              // 64 KB

    hipMemsetAsync(sumx, 0, 512 * 16 * sizeof(float), stream);
    hipMemsetAsync(out, 0, 8192 * sizeof(float), stream);

    k_sumx<<<dim3(16, 16), 256, 0, stream>>>(x, sumx);
    k_prepA<<<512, 256, 0, stream>>>(m1w, bent, Abf, bias2);
    k_conv_W<<<dim3(32, 32), 256, 0, stream>>>(Went, WT);
    k_gemm1<<<dim3(8, 4, 8), 512, 0, stream>>>(Abf, WT, CpL, CpR);
    k_reduce<<<512, 256, 0, stream>>>(CpL, CpR, M1f, M2t);
    k_cb<<<dim3(16, 8), 256, 0, stream>>>(sumx, M2t, bias2, m1b, cb);
    k_gemm2<<<256, 512, 0, stream>>>(x, M1f, cb, lng, lnb, m2w, m2b, logits);
    k_softmax<<<16, 256, 0, stream>>>(logits, out + 8192);
    k_context<<<dim3(16, 16), 256, 0, stream>>>(x, out + 8192, out);
}